// Round 1
// baseline (439.566 us; speedup 1.0000x reference)
//
#include <hip/hip_runtime.h>

#define SIDE 9
#define STATE 81
#define NA 5
#define NJ (STATE * NA)   // 405
#define H1 32
#define H2 32

// Compile-time inflow destination table: j = s*NA + a  ->  dest state.
struct DstTab { int v[NJ]; };
constexpr DstTab make_dst() {
    DstTab t{};
    const int dr[NA] = {0, -1, 1, 0, 0};
    const int dc[NA] = {0, 0, 0, -1, 1};
    for (int s = 0; s < STATE; ++s) {
        int r = s / SIDE, c = s % SIDE;
        for (int a = 0; a < NA; ++a) {
            int nr = r + dr[a], nc = c + dc[a];
            int d = (nr >= 0 && nr < SIDE && nc >= 0 && nc < SIDE) ? nr * SIDE + nc : s;
            t.v[s * NA + a] = d;
        }
    }
    return t;
}
constexpr DstTab DST = make_dst();

__global__ __launch_bounds__(256) void grid_vpn_kernel(
    const float* __restrict__ obs,        // (B, 243)
    const float* __restrict__ af,         // (B, 405)
    const float* __restrict__ W1,         // (81, 32)
    const float* __restrict__ W2,         // (32, 32)
    const float* __restrict__ W3,         // (32, 1)
    const float* __restrict__ b3,         // (1,)
    float* __restrict__ out,              // [sym(B) | ir(B) | nr(B) | nsc(B*81)]
    int B)
{
    int b = blockIdx.x * blockDim.x + threadIdx.x;
    if (b >= B) return;

    // ---- scatter-add: nsc[dst[j]] += af[b, j], all indices compile-time ----
    const float* afr = af + (size_t)b * NJ;
    float nsc[STATE];
#pragma unroll
    for (int d = 0; d < STATE; ++d) nsc[d] = 0.0f;
#pragma unroll
    for (int j = 0; j < NJ; ++j) {
        nsc[DST.v[j]] += afr[j];
    }

    // ---- immediate reward: sum(min(nsc, demand)) ----
    const float* dem = obs + (size_t)b * (3 * STATE) + 2 * STATE;
    float ir = 0.0f;
#pragma unroll
    for (int d = 0; d < STATE; ++d) ir += fminf(nsc[d], dem[d]);

    // ---- write nsc early (frees pressure after layer 1 consumes it) ----
    float* nso = out + 3 * (size_t)B + (size_t)b * STATE;
#pragma unroll
    for (int d = 0; d < STATE; ++d) nso[d] = nsc[d];

    // ---- layer 1: x1 = relu(nsc @ W1)  (81x32), W1 via scalar loads ----
    float x1[H1];
#pragma unroll
    for (int j = 0; j < H1; ++j) x1[j] = 0.0f;
#pragma unroll
    for (int d = 0; d < STATE; ++d) {
        float v = nsc[d];
#pragma unroll
        for (int j = 0; j < H1; ++j) x1[j] = fmaf(v, W1[d * H1 + j], x1[j]);
    }
#pragma unroll
    for (int j = 0; j < H1; ++j) x1[j] = fmaxf(x1[j], 0.0f);

    // ---- layer 2: x2 = relu(x1 @ W2)  (32x32) ----
    float x2[H2];
#pragma unroll
    for (int j = 0; j < H2; ++j) x2[j] = 0.0f;
#pragma unroll
    for (int k = 0; k < H1; ++k) {
        float v = x1[k];
#pragma unroll
        for (int j = 0; j < H2; ++j) x2[j] = fmaf(v, W2[k * H2 + j], x2[j]);
    }
#pragma unroll
    for (int j = 0; j < H2; ++j) x2[j] = fmaxf(x2[j], 0.0f);

    // ---- layer 3: nr = x2 @ W3 + b3 ----
    float nr = b3[0];
#pragma unroll
    for (int k = 0; k < H2; ++k) nr = fmaf(x2[k], W3[k], nr);

    // ---- scalar outputs ----
    out[b] = ir + nr;            // symbolic_val
    out[(size_t)B + b] = ir;     // immediate_reward
    out[2 * (size_t)B + b] = nr; // next_return
}

extern "C" void kernel_launch(void* const* d_in, const int* in_sizes, int n_in,
                              void* d_out, int out_size, void* d_ws, size_t ws_size,
                              hipStream_t stream) {
    const float* obs = (const float*)d_in[0];
    const float* ac  = (const float*)d_in[1];
    const float* W1  = (const float*)d_in[2];
    const float* W2  = (const float*)d_in[3];
    const float* W3  = (const float*)d_in[4];
    const float* b3  = (const float*)d_in[5];
    float* out = (float*)d_out;

    int B = in_sizes[0] / (3 * STATE);
    int block = 256;
    int grid = (B + block - 1) / block;
    hipLaunchKernelGGL(grid_vpn_kernel, dim3(grid), dim3(block), 0, stream,
                       obs, ac, W1, W2, W3, b3, out, B);
}